// Round 9
// baseline (189.114 us; speedup 1.0000x reference)
//
#include <hip/hip_runtime.h>
#include <math.h>

#define NB 64
#define NT 512
#define HID 8192
#define NC 64
#define NH 4
#define HD 16
#define GD 64
#define IN_DIM 128
#define TSPLIT 4

typedef float f32x4 __attribute__((ext_vector_type(4)));

// ---------------------------------------------------------------------------
// Kernel 1: temporal partial-sum pooling, contiguous-stream layout (R7 best).
// ---------------------------------------------------------------------------
__global__ __launch_bounds__(1024) void pool_kernel(const float* __restrict__ H,
                                                    float* __restrict__ part,
                                                    int ts_count) {
    const int ts = blockIdx.x;
    const int b = blockIdx.y;
    const int tid = threadIdx.x;
    const int rows = NT / ts_count;
    const f32x4* src = reinterpret_cast<const f32x4*>(H + (size_t)b * NT * HID) +
                       (size_t)(ts * rows) * (HID / 4);
    f32x4 a0 = (f32x4)0.f;
    f32x4 a1 = (f32x4)0.f;
#pragma unroll 4
    for (int t = 0; t < rows; ++t) {
        f32x4 v0 = __builtin_nontemporal_load(&src[(size_t)t * (HID / 4) + tid]);
        f32x4 v1 = __builtin_nontemporal_load(&src[(size_t)t * (HID / 4) + tid + 1024]);
        a0 += v0;
        a1 += v1;
    }
    f32x4* dst = reinterpret_cast<f32x4*>(part + ((size_t)ts * NB + b) * HID);
    dst[tid] = a0;
    dst[tid + 1024] = a1;
}

// ---------------------------------------------------------------------------
// Kernel 2: fused tail. One block per batch, 1024 threads, 52.2KB LDS with
// phase overlays. fold -> embed GEMM (We in f-halves, reg acc) -> Wh GEMM ->
// s1/s2 -> stats -> attn write + PV -> elu -> mean -> readout.
// ---------------------------------------------------------------------------
#define SNI 132   // ni row stride (conflict-free broadcast reads)
#define SP  68    // padded stride for 64-wide tiles

// float offsets into smem (overlays annotated)
#define OFF_NI    0        // [64][132]=8448   phase A
#define OFF_NODES 0        // [64][68]=4352    phase B   (over ni)
#define OFF_HO    0        // [64][68]=4352    phase C   (over nodes)
#define OFF_WRT   0        // [64][132]=8448   phase D   (over ho+Wh)
#define OFF_WH    4352     // [64][68]=4352    phases B..C
#define OFF_WE    8704     // [64][68]=4352    phase A (f-halves)
#define OFF_WW    8704     // [64][68]=4352    phase B   (over We)
#define OFF_S1    8704     // [4][64]=256      phase C   (over Ww)
#define OFF_S2    8960     // [4][64]=256
#define OFF_PM    9216     // [4][256]=1024    (reused for mean partials)
#define OFF_PS    10240    // [4][256]=1024
#define OFF_M     11264    // [256]
#define OFF_INV   11520    // [256]
#define OFF_MEAN  11776    // [64]
#define SMEM_FLOATS 13056  // 52.2 KB

__global__ __launch_bounds__(1024) void tail_kernel(
    const float* __restrict__ part,      // [TS, B, HID]
    const float* __restrict__ W_embed,   // [GD, IN_DIM]
    const float* __restrict__ b_embed,   // [GD]
    const float* __restrict__ Wh_w,      // [NH*HD, GD]
    const float* __restrict__ a_w,       // [NH, 2*HD]
    const float* __restrict__ Wr,        // [IN_DIM, GD]
    const float* __restrict__ br,        // [IN_DIM]
    float* __restrict__ out_g,           // [B, IN_DIM]
    float* __restrict__ out_attn,        // [B, NH, C, C]
    int ts_count)
{
    __shared__ float smem[SMEM_FLOATS];
    const int tid = threadIdx.x;
    const int b = blockIdx.x;

    // ---- A: fold partials -> ni, stage We half0 (transposed [f][g], pad 68)
#pragma unroll
    for (int k = 0; k < 2; ++k) {
        int idx4 = tid + k * 1024;                 // 2048 f32x4 total
        int c = idx4 >> 5, f4 = (idx4 & 31) << 2;
        f32x4 s = (f32x4)0.f;
        for (int ts = 0; ts < ts_count; ++ts)
            s += reinterpret_cast<const f32x4*>(part + ((size_t)ts * NB + b) * HID)[idx4];
        *reinterpret_cast<f32x4*>(&smem[OFF_NI + c * SNI + f4]) = s * (1.0f / NT);
    }
#pragma unroll
    for (int k = 0; k < 4; ++k) {
        int idx = tid + k * 1024;                  // 4096 elems: f in [0,64)
        int g = idx >> 6, f = idx & 63;
        smem[OFF_WE + f * SP + g] = W_embed[g * IN_DIM + f];   // coalesced global
    }
    __syncthreads();

    // ---- GEMM1 (nodes = ni @ We^T + b), acc in regs across two We halves
    const int c_g = tid >> 4;              // 0..63  (output row)
    const int g4 = (tid & 15) << 2;        // 0..60  (output col quad)
    f32x4 acc1 = *reinterpret_cast<const f32x4*>(&b_embed[g4]);
#pragma unroll 8
    for (int f = 0; f < 64; ++f) {
        float n = smem[OFF_NI + c_g * SNI + f];                          // bcast, cf
        f32x4 w = *reinterpret_cast<const f32x4*>(&smem[OFF_WE + f * SP + g4]);
        acc1 += n * w;
    }
    __syncthreads();
#pragma unroll
    for (int k = 0; k < 4; ++k) {
        int idx = tid + k * 1024;                  // f in [64,128)
        int g = idx >> 6, f = idx & 63;
        smem[OFF_WE + f * SP + g] = W_embed[g * IN_DIM + 64 + f];
    }
    __syncthreads();
#pragma unroll 8
    for (int f = 0; f < 64; ++f) {
        float n = smem[OFF_NI + c_g * SNI + 64 + f];
        f32x4 w = *reinterpret_cast<const f32x4*>(&smem[OFF_WE + f * SP + g4]);
        acc1 += n * w;
    }
    __syncthreads();   // ni + We dead

    // ---- B: write nodes (over ni), stage Ww transposed (over We)
    *reinterpret_cast<f32x4*>(&smem[OFF_NODES + c_g * SP + g4]) = acc1;
#pragma unroll
    for (int k = 0; k < 4; ++k) {
        int idx = tid + k * 1024;
        int ho = idx >> 6, g = idx & 63;           // Wh_w[ho][g] -> [g][ho]
        smem[OFF_WW + g * SP + ho] = Wh_w[ho * GD + g];
    }
    __syncthreads();

    // ---- GEMM2: Wh = nodes @ Ww^T
    f32x4 acc2 = (f32x4)0.f;
#pragma unroll 8
    for (int g = 0; g < GD; ++g) {
        float n = smem[OFF_NODES + c_g * SP + g];                        // bcast, cf
        f32x4 w = *reinterpret_cast<const f32x4*>(&smem[OFF_WW + g * SP + g4]);
        acc2 += n * w;
    }
    *reinterpret_cast<f32x4*>(&smem[OFF_WH + c_g * SP + g4]) = acc2;
    __syncthreads();   // Ww dead; Wh live

    // ---- s1/s2 (over Ww region)
    if (tid < 256) {
        int c = tid >> 2, h = tid & 3;
        float a1 = 0.f, a2 = 0.f;
#pragma unroll
        for (int o = 0; o < HD; ++o) {
            float w = smem[OFF_WH + c * SP + h * HD + o];
            a1 += w * a_w[h * 2 * HD + o];
            a2 += w * a_w[h * 2 * HD + HD + o];
        }
        smem[OFF_S1 + h * NC + c] = a1;
        smem[OFF_S2 + h * NC + c] = a2;
    }
    __syncthreads();

    // ---- stats: row r = h*64+i (tid&255), quarter q = tid>>8
    {
        const int r = tid & 255, q = tid >> 8;
        const int i = r & 63, h = r >> 6;
        const float s1 = smem[OFF_S1 + h * NC + i];
        float pm = -1e30f;
#pragma unroll
        for (int jj = 0; jj < 16; ++jj) {
            float x = s1 + smem[OFF_S2 + h * NC + q * 16 + jj];
            float e = x > 0.f ? x : 0.2f * x;
            pm = fmaxf(pm, e);
        }
        smem[OFF_PM + q * 256 + r] = pm;
        __syncthreads();
        const float m = fmaxf(fmaxf(smem[OFF_PM + r], smem[OFF_PM + 256 + r]),
                              fmaxf(smem[OFF_PM + 512 + r], smem[OFF_PM + 768 + r]));
        float ps = 0.f;
#pragma unroll
        for (int jj = 0; jj < 16; ++jj) {
            float x = s1 + smem[OFF_S2 + h * NC + q * 16 + jj];
            float e = x > 0.f ? x : 0.2f * x;
            ps += __expf(e - m);
        }
        smem[OFF_PS + q * 256 + r] = ps;
        __syncthreads();
        if (tid < 256) {
            smem[OFF_M + tid] = m;
            smem[OFF_INV + tid] = 1.0f / (smem[OFF_PS + tid] + smem[OFF_PS + 256 + tid] +
                                          smem[OFF_PS + 512 + tid] + smem[OFF_PS + 768 + tid]);
        }
    }
    __syncthreads();

    // ---- attn global write (coalesced f32x4), 4 per thread
    f32x4* attn_b = reinterpret_cast<f32x4*>(out_attn + (size_t)b * NH * NC * NC);
#pragma unroll
    for (int k = 0; k < 4; ++k) {
        int idx4 = tid + k * 1024;                 // h<<10 | i<<4 | j4
        int h = idx4 >> 10, i = (idx4 >> 4) & 63, j = (idx4 & 15) << 2;
        int r = h * 64 + i;
        float s1 = smem[OFF_S1 + h * NC + i];
        float m = smem[OFF_M + r], inv = smem[OFF_INV + r];
        f32x4 p;
        {
            float x = s1 + smem[OFF_S2 + h * NC + j + 0];
            float e = x > 0.f ? x : 0.2f * x; p.x = __expf(e - m) * inv;
        }
        {
            float x = s1 + smem[OFF_S2 + h * NC + j + 1];
            float e = x > 0.f ? x : 0.2f * x; p.y = __expf(e - m) * inv;
        }
        {
            float x = s1 + smem[OFF_S2 + h * NC + j + 2];
            float e = x > 0.f ? x : 0.2f * x; p.z = __expf(e - m) * inv;
        }
        {
            float x = s1 + smem[OFF_S2 + h * NC + j + 3];
            float e = x > 0.f ? x : 0.2f * x; p.w = __expf(e - m) * inv;
        }
        attn_b[idx4] = p;
    }

    // ---- PV + elu -> ho (over nodes region; Wh still live)
    {
        const int og = tid & 3, i = (tid >> 2) & 63, h = tid >> 8;
        const int r = h * 64 + i;
        const float s1 = smem[OFF_S1 + h * NC + i];
        const float m = smem[OFF_M + r], inv = smem[OFF_INV + r];
        f32x4 a = (f32x4)0.f;
        for (int j = 0; j < NC; ++j) {
            float x = s1 + smem[OFF_S2 + h * NC + j];       // uniform: bcast
            float e = x > 0.f ? x : 0.2f * x;
            float p = __expf(e - m) * inv;
            f32x4 w = *reinterpret_cast<const f32x4*>(
                &smem[OFF_WH + j * SP + h * HD + og * 4]);  // 4 addrs: bcast
            a += p * w;
        }
        f32x4 o;
        o.x = a.x > 0.f ? a.x : expm1f(a.x);
        o.y = a.y > 0.f ? a.y : expm1f(a.y);
        o.z = a.z > 0.f ? a.z : expm1f(a.z);
        o.w = a.w > 0.f ? a.w : expm1f(a.w);
        *reinterpret_cast<f32x4*>(&smem[OFF_HO + i * SP + h * HD + og * 4]) = o;
    }
    __syncthreads();

    // ---- node-mean (quartered; reuse PM region)
    if (tid < 256) {
        int g = tid & 63, q = tid >> 6;
        float s = 0.f;
#pragma unroll
        for (int ii = 0; ii < 16; ++ii)
            s += smem[OFF_HO + (q * 16 + ii) * SP + g];     // 2-way: free
        smem[OFF_PM + q * 64 + g] = s;
    }
    __syncthreads();
    if (tid < 64)
        smem[OFF_MEAN + tid] = (smem[OFF_PM + tid] + smem[OFF_PM + 64 + tid] +
                                smem[OFF_PM + 128 + tid] + smem[OFF_PM + 192 + tid]) *
                               (1.0f / NC);
    __syncthreads();

    // ---- D: readout (WrT over ho+Wh, both dead)
#pragma unroll
    for (int k = 0; k < 8; ++k) {
        int idx = tid + k * 1024;
        int io = idx >> 6, g = idx & 63;                    // Wr[io][g] -> [g][io]
        smem[OFF_WRT + g * 132 + io] = Wr[io * GD + g];
    }
    __syncthreads();
    if (tid < IN_DIM) {
        float acc = br[tid];
#pragma unroll 8
        for (int g = 0; g < GD; ++g)
            acc += smem[OFF_MEAN + g] * smem[OFF_WRT + g * 132 + tid];  // 2-way: free
        out_g[(size_t)b * IN_DIM + tid] = fmaxf(acc, 0.f);
    }
}

extern "C" void kernel_launch(void* const* d_in, const int* in_sizes, int n_in,
                              void* d_out, int out_size, void* d_ws, size_t ws_size,
                              hipStream_t stream) {
    const float* H       = (const float*)d_in[0];
    const float* W_embed = (const float*)d_in[1];
    const float* b_embed = (const float*)d_in[2];
    const float* Wh_w    = (const float*)d_in[3];
    const float* a_w     = (const float*)d_in[4];
    const float* Wr      = (const float*)d_in[5];
    const float* br      = (const float*)d_in[6];
    float* out = (float*)d_out;
    float* out_attn = out + NB * IN_DIM;

    const size_t need4 = (size_t)TSPLIT * NB * HID * sizeof(float);   // 8 MB
    const int ts = (ws_size >= need4) ? TSPLIT : 1;
    float* part = (float*)d_ws;                                       // [ts, B, HID]

    pool_kernel<<<dim3(ts, NB), dim3(1024), 0, stream>>>(H, part, ts);
    tail_kernel<<<dim3(NB), dim3(1024), 0, stream>>>(
        part, W_embed, b_embed, Wh_w, a_w, Wr, br, out, out_attn, ts);
}